// Round 10
// baseline (403.182 us; speedup 1.0000x reference)
//
#include <hip/hip_runtime.h>
#include <hip/hip_bf16.h>

// ScaledDotAttention: out = softmax_causal((X Wq)(X Wk)^T / 32) (X Wv) Wo + bo
// B=8, T=2048, D=DK=DV=1024. bf16 MFMA pipeline, materialized S/P in ws.
// R10: revert R9 algebra (measured regression). gemm_k = m97-analog:
//     128x128 tile, BK=64, 256 thr / 4 waves, SINGLE 32 KiB LDS buffer,
//     plain stage->sync->compute loop; rely on 4 blocks/CU TLP to hide
//     drains (m114/m97). Swizzle + gload + setprio + XCD swizzle kept.

typedef __attribute__((ext_vector_type(8))) short bf16x8;
typedef __attribute__((ext_vector_type(4))) float f32x4;

#define DEVI __device__ __forceinline__
#define VM_GATE(n) asm volatile("s_waitcnt vmcnt(" #n ")" ::: "memory")

DEVI unsigned short f2bf(float f) {
  union { float f; unsigned u; } v; v.f = f;
  unsigned r = v.u + 0x7FFFu + ((v.u >> 16) & 1u);
  return (unsigned short)(r >> 16);
}

DEVI unsigned pkbf(float a, float b) {
  unsigned r;
  asm("v_cvt_pk_bf16_f32 %0, %1, %2" : "=v"(r) : "v"(a), "v"(b));
  return r;
}

DEVI void load_lds16(const void* g, void* l) {
  __builtin_amdgcn_global_load_lds(
      (const __attribute__((address_space(1))) unsigned int*)g,
      (__attribute__((address_space(3))) unsigned int*)l,
      16, 0, 0);
}

constexpr int BM = 128, BN = 128, BK = 64;

// C[M][N] = A[M][K] * Bt[N][K]^T  (A bf16 or f32; Bt bf16 row=n contiguous k)
// LDS tile [128 rows][8 slots of 16B], slot' = slot ^ (row&7) (involution).
template<bool A_F32, bool OUT_F32, bool OUT_TRANS, bool DO_BIAS, bool DO_SCALE,
         bool DO_CSKIP, bool DO_KCLAMP>
__global__ __launch_bounds__(256) void gemm_k(
    const void* __restrict__ Ap, long lda, long sAz,
    const unsigned short* __restrict__ Bt, long ldb, long sBz,
    void* __restrict__ Cp, long ldc, long sCz,
    const float* __restrict__ bias, float scale,
    const int* __restrict__ maskp, int Kdim)
{
  // bijective XCD-chunked block swizzle (all grids have nwg % 8 == 0)
  const int nx = gridDim.x, ny = gridDim.y;
  int bid = (blockIdx.z * ny + blockIdx.y) * nx + blockIdx.x;
  const int nwg = nx * ny * (int)gridDim.z;
  if ((nwg & 7) == 0) bid = (bid & 7) * (nwg >> 3) + (bid >> 3);
  const int bx = bid % nx;
  const int t1 = bid / nx;
  const int by = t1 % ny;
  const int z  = t1 / ny;

  const int n0 = bx * BN;
  const int m0 = by * BM;
  if constexpr (DO_CSKIP) {
    if (maskp[0] && n0 > m0 + (BM - 1)) return;  // tile fully above diagonal
  }
  int Keff = Kdim;
  if constexpr (DO_KCLAMP) {
    if (maskp[0]) Keff = min(Kdim, m0 + BM);     // P lower-triangular
  }

  __shared__ alignas(16) char As[16384];
  __shared__ alignas(16) char Bs[16384];

  const int tid  = threadIdx.x;
  const int lane = tid & 63;
  const int w    = tid >> 6;
  const int wr   = w >> 1, wc = w & 1;   // 2x2 waves; per-wave 64(M) x 64(N)
  const int la   = lane & 15;
  const int q0   = lane >> 4;

  f32x4 acc[4][4];
  const f32x4 z4 = {0.f, 0.f, 0.f, 0.f};
#pragma unroll
  for (int mi = 0; mi < 4; ++mi)
#pragma unroll
    for (int ni = 0; ni < 4; ++ni) acc[mi][ni] = z4;

  const unsigned short* Ag0 = (const unsigned short*)Ap + (size_t)z * sAz + (size_t)m0 * lda;
  const float*          Af0 = (const float*)Ap + (size_t)z * sAz + (size_t)m0 * lda;
  const unsigned short* Bg0 = Bt + (size_t)z * sBz + (size_t)n0 * ldb;

  const int nt = Keff / BK;
  for (int t = 0; t < nt; ++t) {
    const int k0 = t * BK;
    if (t) __syncthreads();          // previous tile fully consumed

    // ---- stage tile t into the single buffer
    if constexpr (A_F32) {
      float4 fr[8];
#pragma unroll
      for (int p = 0; p < 8; ++p) {
        int idx = tid + p * 256;
        int row = idx >> 4, c4 = idx & 15;       // 16 float4-cells per row
        fr[p] = *(const float4*)(Af0 + (size_t)row * lda + k0 + c4 * 4);
      }
#pragma unroll
      for (int p = 0; p < 4; ++p) {              // B via gload (pre-swizzled src)
        int cb = p * 256 + w * 64;
        int c  = cb + lane;
        int row = c >> 3, gs = (c & 7) ^ (row & 7);
        load_lds16(Bg0 + (size_t)row * ldb + k0 + gs * 8, Bs + cb * 16);
      }
      VM_GATE(4);                                // f32 regs done; B's 4 in flight
#pragma unroll
      for (int p = 0; p < 8; ++p) {
        int idx = tid + p * 256;
        int row = idx >> 4, c4 = idx & 15;
        ushort4 h;
        h.x = f2bf(fr[p].x); h.y = f2bf(fr[p].y);
        h.z = f2bf(fr[p].z); h.w = f2bf(fr[p].w);
        int byte = ((((c4 >> 1) ^ (row & 7)) << 4)) | ((c4 & 1) << 3);
        *(ushort4*)(As + row * 128 + byte) = h;
      }
    } else {
#pragma unroll
      for (int p = 0; p < 4; ++p) {
        int cb = p * 256 + w * 64;
        int c  = cb + lane;
        int row = c >> 3, gs = (c & 7) ^ (row & 7);
        load_lds16(Ag0 + (size_t)row * lda + k0 + gs * 8, As + cb * 16);
      }
#pragma unroll
      for (int p = 0; p < 4; ++p) {
        int cb = p * 256 + w * 64;
        int c  = cb + lane;
        int row = c >> 3, gs = (c & 7) ^ (row & 7);
        load_lds16(Bg0 + (size_t)row * ldb + k0 + gs * 8, Bs + cb * 16);
      }
    }
    __syncthreads();                 // full drain: tile resident

    // ---- compute: 32 MFMA
#pragma unroll
    for (int kk = 0; kk < 2; ++kk) {
      bf16x8 af[4], bfv[4];
#pragma unroll
      for (int mi = 0; mi < 4; ++mi) {
        int r = wr * 64 + mi * 16 + la;
        int slot = kk * 4 + q0;
        af[mi] = *(const bf16x8*)(As + r * 128 + ((slot ^ (r & 7)) << 4));
      }
#pragma unroll
      for (int ni = 0; ni < 4; ++ni) {
        int r = wc * 64 + ni * 16 + la;
        int slot = kk * 4 + q0;
        bfv[ni] = *(const bf16x8*)(Bs + r * 128 + ((slot ^ (r & 7)) << 4));
      }
      __builtin_amdgcn_s_setprio(1);
#pragma unroll
      for (int mi = 0; mi < 4; ++mi)
#pragma unroll
        for (int ni = 0; ni < 4; ++ni)
          acc[mi][ni] = __builtin_amdgcn_mfma_f32_16x16x32_bf16(af[mi], bfv[ni], acc[mi][ni], 0, 0, 0);
      __builtin_amdgcn_s_setprio(0);
    }
  }

  // epilogue: D frag (verified m89): col = lane&15, row = (lane>>4)*4 + reg
#pragma unroll
  for (int ni = 0; ni < 4; ++ni) {
    const int n = n0 + wc * 64 + ni * 16 + la;
    float bv = 0.f;
    if constexpr (DO_BIAS) bv = bias[n];
#pragma unroll
    for (int mi = 0; mi < 4; ++mi) {
      const int m = m0 + wr * 64 + mi * 16 + (q0 << 2);
      f32x4 c = acc[mi][ni];
      if constexpr (DO_SCALE) c = c * scale;
      if constexpr (DO_BIAS)  c = c + bv;
      if constexpr (OUT_TRANS) {
        unsigned short* C = (unsigned short*)Cp + (size_t)z * sCz + (size_t)n * ldc + m;
        ushort4 h;
        h.x = f2bf(c[0]); h.y = f2bf(c[1]); h.z = f2bf(c[2]); h.w = f2bf(c[3]);
        *(ushort4*)C = h;
      } else if constexpr (OUT_F32) {
        float* C = (float*)Cp + (size_t)z * sCz + (size_t)m * ldc + n;
#pragma unroll
        for (int j = 0; j < 4; ++j) C[(size_t)j * ldc] = c[j];
      } else {
        unsigned short* C = (unsigned short*)Cp + (size_t)z * sCz + (size_t)m * ldc + n;
#pragma unroll
        for (int j = 0; j < 4; ++j) C[(size_t)j * ldc] = f2bf(c[j]);
      }
    }
  }
}

// Wt[n][k] = bf16(W[k][n]), 4 weight matrices, z selects which
__global__ __launch_bounds__(256) void wtrans_k(
    const float* __restrict__ W0, const float* __restrict__ W1,
    const float* __restrict__ W2, const float* __restrict__ W3,
    unsigned short* __restrict__ T0, unsigned short* __restrict__ T1,
    unsigned short* __restrict__ T2, unsigned short* __restrict__ T3)
{
  const float* W = blockIdx.z == 0 ? W0 : blockIdx.z == 1 ? W1
                 : blockIdx.z == 2 ? W2 : W3;
  unsigned short* Wt = blockIdx.z == 0 ? T0 : blockIdx.z == 1 ? T1
                     : blockIdx.z == 2 ? T2 : T3;
  __shared__ unsigned short L[64][80];
  const int n0 = blockIdx.x * 64, k0 = blockIdx.y * 64;
  const int tid = threadIdx.x;
#pragma unroll
  for (int p = 0; p < 4; ++p) {
    int idx = tid + p * 256;
    int r = idx >> 4, c4 = idx & 15;
    float4 v = *(const float4*)(W + (size_t)(k0 + r) * 1024 + n0 + c4 * 4);
    L[c4 * 4 + 0][r] = f2bf(v.x);
    L[c4 * 4 + 1][r] = f2bf(v.y);
    L[c4 * 4 + 2][r] = f2bf(v.z);
    L[c4 * 4 + 3][r] = f2bf(v.w);
  }
  __syncthreads();
#pragma unroll
  for (int p = 0; p < 2; ++p) {
    int idx = tid + p * 256;
    int n = idx >> 3, c8 = idx & 7;
    int4 v = *(const int4*)(&L[n][c8 * 8]);
    *(int4*)(Wt + (size_t)(n0 + n) * 1024 + k0 + c8 * 8) = v;
  }
}

// row softmax over S[16384][2048] f32; writes bf16 P in place (row-start).
// Causal: read only cols < lim; write zeros up to the 128-tile boundary
// (PV's K-clamp with BM=128 never reads beyond it).
__global__ __launch_bounds__(256) void softmax_k(float* __restrict__ S,
                                                 const int* __restrict__ maskp)
{
  const int row = blockIdx.x;
  const int t = row & 2047;
  const int msk = maskp[0];
  const int lim  = msk ? (t + 1) : 2048;
  const int wlim = msk ? ((t & ~127) + 128) : 2048;
  float* Srow = S + (size_t)row * 2048;
  const int tid = threadIdx.x;
  const int cbase = tid * 8;

  float v[8];
  if (cbase < lim) {
    float4 a = *(const float4*)(Srow + cbase);
    float4 b = *(const float4*)(Srow + cbase + 4);
    v[0] = a.x; v[1] = a.y; v[2] = a.z; v[3] = a.w;
    v[4] = b.x; v[5] = b.y; v[6] = b.z; v[7] = b.w;
#pragma unroll
    for (int j = 0; j < 8; ++j)
      if (cbase + j >= lim) v[j] = -__builtin_inff();
  } else {
#pragma unroll
    for (int j = 0; j < 8; ++j) v[j] = -__builtin_inff();
  }

  float mx = v[0];
#pragma unroll
  for (int j = 1; j < 8; ++j) mx = fmaxf(mx, v[j]);
#pragma unroll
  for (int off = 32; off; off >>= 1) mx = fmaxf(mx, __shfl_xor(mx, off, 64));

  __shared__ float redm[4], reds[4];
  const int wid = tid >> 6;
  if ((tid & 63) == 0) redm[wid] = mx;
  __syncthreads();
  mx = fmaxf(fmaxf(redm[0], redm[1]), fmaxf(redm[2], redm[3]));

  float e[8], s = 0.f;
#pragma unroll
  for (int j = 0; j < 8; ++j) { e[j] = __expf(v[j] - mx); s += e[j]; }
#pragma unroll
  for (int off = 32; off; off >>= 1) s += __shfl_xor(s, off, 64);
  if ((tid & 63) == 0) reds[wid] = s;
  __syncthreads();
  s = reds[0] + reds[1] + reds[2] + reds[3];
  const float inv = 1.0f / s;

  if (cbase < wlim) {
    unsigned short* Prow = (unsigned short*)Srow;
    unsigned pk[4];
#pragma unroll
    for (int q = 0; q < 4; ++q)
      pk[q] = (unsigned)f2bf(e[2 * q] * inv) | ((unsigned)f2bf(e[2 * q + 1] * inv) << 16);
    int4 o; o.x = (int)pk[0]; o.y = (int)pk[1]; o.z = (int)pk[2]; o.w = (int)pk[3];
    *(int4*)(Prow + (size_t)cbase) = o;
  }
}

extern "C" void kernel_launch(void* const* d_in, const int* in_sizes, int n_in,
                              void* d_out, int out_size, void* d_ws, size_t ws_size,
                              hipStream_t stream)
{
  const float* query  = (const float*)d_in[0];
  const float* keys   = (const float*)d_in[1];
  const float* values = (const float*)d_in[2];
  const float* Wq = (const float*)d_in[3];
  const float* bq = (const float*)d_in[4];
  const float* Wk = (const float*)d_in[5];
  const float* bk = (const float*)d_in[6];
  const float* Wv = (const float*)d_in[7];
  const float* bv = (const float*)d_in[8];
  const float* Wo = (const float*)d_in[9];
  const float* bo = (const float*)d_in[10];
  const int* maskp = (const int*)d_in[11];
  float* out = (float*)d_out;

  char* ws = (char*)d_ws;
  const size_t MB = 1ull << 20;
  unsigned short* wt_q = (unsigned short*)(ws + 0 * MB);
  unsigned short* wt_k = (unsigned short*)(ws + 2 * MB);
  unsigned short* wt_v = (unsigned short*)(ws + 4 * MB);
  unsigned short* wt_o = (unsigned short*)(ws + 6 * MB);
  unsigned short* Qb   = (unsigned short*)(ws + 8 * MB);    // 32 MiB [16384][1024]
  unsigned short* Kb   = (unsigned short*)(ws + 40 * MB);   // 32 MiB
  unsigned short* Vt   = (unsigned short*)(ws + 72 * MB);   // 32 MiB [8][1024][2048]
  float*          S    = (float*)(ws + 104 * MB);           // 128 MiB [16384][2048]
  unsigned short* ctx  = Qb;  // context aliases Q (Q dead after scores)

  const dim3 blk(256);
  const long sXT = 2048l * 1024;   // per-batch stride of [T,1024] tensors

  // weight transpose+convert (one launch, z = which matrix)
  wtrans_k<<<dim3(16, 16, 4), dim3(256), 0, stream>>>(
      Wq, Wk, Wv, Wo, wt_q, wt_k, wt_v, wt_o);

  // projections (A = f32 input, fused cvt). V written transposed per batch.
  gemm_k<true, false, false, true, false, false, false><<<dim3(8, 16, 8), blk, 0, stream>>>(
      query, 1024, sXT, wt_q, 1024, 0, Qb, 1024, sXT, bq, 1.f, nullptr, 1024);
  gemm_k<true, false, false, true, false, false, false><<<dim3(8, 16, 8), blk, 0, stream>>>(
      keys, 1024, sXT, wt_k, 1024, 0, Kb, 1024, sXT, bk, 1.f, nullptr, 1024);
  gemm_k<true, false, true, true, false, false, false><<<dim3(8, 16, 8), blk, 0, stream>>>(
      values, 1024, sXT, wt_v, 1024, 0, Vt, 2048, 1024l * 2048, bv, 1.f, nullptr, 1024);

  // scores: S[b][t][s] = Q[b] K[b]^T / 32, upper tiles skipped when masked
  gemm_k<false, true, false, false, true, true, false><<<dim3(16, 16, 8), blk, 0, stream>>>(
      Qb, 1024, sXT, Kb, 1024, sXT, S, 2048, 2048l * 2048, nullptr, 0.03125f, maskp, 1024);

  // softmax rows -> bf16 P in place (stride 4096 elems)
  softmax_k<<<dim3(16384), dim3(256), 0, stream>>>(S, maskp);

  // context[b][t][d] = P[b] @ V[b]  (A = P bf16, lda 4096; Bt = Vt; K causal-clamped)
  gemm_k<false, false, false, false, false, false, true><<<dim3(8, 16, 8), blk, 0, stream>>>(
      (unsigned short*)S, 4096, 2048l * 4096, Vt, 2048, 1024l * 2048,
      ctx, 1024, sXT, nullptr, 1.f, maskp, 2048);

  // out = context @ Wo + bo (f32 out)
  gemm_k<false, true, false, true, false, false, false><<<dim3(8, 16, 8), blk, 0, stream>>>(
      ctx, 1024, sXT, wt_o, 1024, 0, out, 1024, sXT, bo, 1.f, nullptr, 1024);
}